// Round 5
// baseline (358.865 us; speedup 1.0000x reference)
//
#include <hip/hip_runtime.h>

#define NS 7
#define NA 131072
#define AEVD 1008
#define KP1 1024
#define N1 256
#define N2 192
#define N3 160

typedef __attribute__((ext_vector_type(8))) short short8;
typedef __attribute__((ext_vector_type(8))) unsigned short ushortx8;
typedef __attribute__((ext_vector_type(4))) unsigned short ushortx4;
typedef __attribute__((ext_vector_type(4))) float f32x4;
typedef __attribute__((ext_vector_type(4))) float fvec4;
typedef unsigned short u16;

__device__ __forceinline__ u16 f2bf(float f) {
  unsigned u = __builtin_bit_cast(unsigned, f);
  u += 0x7fffu + ((u >> 16) & 1u);
  return (u16)(u >> 16);
}
__device__ __forceinline__ float bf2f(u16 h) {
  return __builtin_bit_cast(float, ((unsigned)h) << 16);
}
__device__ __forceinline__ float celu_f(float x) {
  return x > 0.f ? x : 0.1f * (__expf(x * 10.f) - 1.f);
}

// ---------------- bucketing ----------------
__global__ void count_kernel(const int* __restrict__ species, int* __restrict__ counts) {
  __shared__ int h[NS];
  if (threadIdx.x < NS) h[threadIdx.x] = 0;
  __syncthreads();
  int i = blockIdx.x * blockDim.x + threadIdx.x;
  if (i < NA) atomicAdd(&h[species[i]], 1);
  __syncthreads();
  if (threadIdx.x < NS) atomicAdd(&counts[threadIdx.x], h[threadIdx.x]);
}

__global__ void scan_kernel(const int* __restrict__ counts, int* __restrict__ offsets,
                            int* __restrict__ cursors, int* __restrict__ blockStart) {
  int off = 0, bs = 0;
  for (int e = 0; e < NS; ++e) {
    offsets[e] = off; cursors[e] = off; blockStart[e] = bs;
    off += counts[e];
    bs += (counts[e] + 63) >> 6;
  }
  offsets[NS] = off; blockStart[NS] = bs;
}

__global__ void scatter_kernel(const int* __restrict__ species, int* __restrict__ cursors,
                               int* __restrict__ idx) {
  __shared__ int h[NS], lb[NS];
  if (threadIdx.x < NS) h[threadIdx.x] = 0;
  __syncthreads();
  int i = blockIdx.x * blockDim.x + threadIdx.x;
  int s = species[i];
  int lpos = atomicAdd(&h[s], 1);
  __syncthreads();
  if (threadIdx.x < NS) lb[threadIdx.x] = atomicAdd(&cursors[threadIdx.x], h[threadIdx.x]);
  __syncthreads();
  idx[lb[s] + lpos] = i;
}

// ---------------- weight convert: dst[e][n][kp] = bf16(src[e][k][n]), zero pad k>=K ----------------
__global__ void convert_w(const float* __restrict__ src, u16* __restrict__ dst,
                          int K, int N, int KP) {
  long total = (long)NS * N * KP;
  for (long i = (long)blockIdx.x * blockDim.x + threadIdx.x; i < total;
       i += (long)gridDim.x * blockDim.x) {
    int kp = (int)(i % KP);
    long t2 = i / KP;
    int n = (int)(t2 % N);
    int e = (int)(t2 / N);
    float v = (kp < K) ? src[((long)e * K + kp) * N + n] : 0.f;
    dst[i] = f2bf(v);
  }
}

// ---------------- fused MLP ----------------
#define AP 264   // A-quarter pitch AND h1 pitch (u16)
#define H2P 200
#define H3P 168

__global__ __launch_bounds__(256, 2) void ani_fused(
    const int* __restrict__ idx, const int* __restrict__ counts,
    const int* __restrict__ offsets, const int* __restrict__ blockStart,
    const float* __restrict__ aev,
    const u16* __restrict__ W1t, const float* __restrict__ b1,
    const u16* __restrict__ W2t, const float* __restrict__ b2,
    const u16* __restrict__ W3t, const float* __restrict__ b3,
    const u16* __restrict__ Wht, const float* __restrict__ bh,
    float* __restrict__ out) {
  // S[0]: A-quarter buf0, later h1, later h3.  S[1]: A-quarter buf1, later h2.
  __shared__ __align__(16) u16 S[2][64 * AP];
  u16* H1 = &S[0][0];
  u16* H2 = &S[1][0];
  u16* H3 = &S[0][0];

  int bid = blockIdx.x;
  if (bid >= blockStart[NS]) return;
  int e = 0;
#pragma unroll
  for (int s = 1; s < NS; ++s)
    if (bid >= blockStart[s]) e = s;
  int t = bid - blockStart[e];
  int base = offsets[e] + (t << 6);
  int mcount = counts[e] - (t << 6);
  if (mcount > 64) mcount = 64;

  int tid = threadIdx.x;
  int lane = tid & 63;
  int w = tid >> 6;
  int lr = lane & 15;
  int kg = lane >> 4;

  // A staging: thread -> row = tid>>2, lane-quad-coalesced 16B units
  int arow = tid >> 2;
  int sub = tid & 3;
  int rrow = arow < mcount ? arow : (mcount - 1);
  const float* aevRow = aev + (size_t)idx[base + rrow] * AEVD;

  const u16* Wb1 = W1t + ((size_t)e * N1 + (w * 64 + lr)) * KP1 + kg * 8;

  fvec4 L[16];
  auto loadQ = [&](int q) {
#pragma unroll
    for (int j = 0; j < 16; ++j) {
      int k = q * 256 + (sub + j * 4) * 4;
      if (k < AEVD) L[j] = *(const fvec4*)(aevRow + k);
      else { fvec4 z = {0.f, 0.f, 0.f, 0.f}; L[j] = z; }
    }
  };
  auto packQ = [&](int b) {
#pragma unroll
    for (int j = 0; j < 16; ++j) {
      ushortx4 p;
      p[0] = f2bf(L[j].x); p[1] = f2bf(L[j].y);
      p[2] = f2bf(L[j].z); p[3] = f2bf(L[j].w);
      *(ushortx4*)&S[b][arow * AP + (sub + j * 4) * 4] = p;
    }
  };

  f32x4 acc[4][4] = {};
  auto computeQ = [&](int q, int b) {
#pragma unroll
    for (int ks = 0; ks < 8; ++ks) {
      short8 af[4], bf[4];
#pragma unroll
      for (int mi = 0; mi < 4; ++mi)
        af[mi] = *(const short8*)&S[b][(mi * 16 + lr) * AP + ks * 32 + kg * 8];
#pragma unroll
      for (int ni = 0; ni < 4; ++ni)
        bf[ni] = *(const short8*)(Wb1 + (size_t)ni * 16 * KP1 + q * 256 + ks * 32);
#pragma unroll
      for (int ni = 0; ni < 4; ++ni)
#pragma unroll
        for (int mi = 0; mi < 4; ++mi)
          acc[mi][ni] = __builtin_amdgcn_mfma_f32_16x16x32_bf16(af[mi], bf[ni], acc[mi][ni], 0, 0, 0);
    }
  };

  // ---------- layer 1: quarter-staged pipeline, 1 barrier per quarter ----------
  loadQ(0); packQ(0); loadQ(1);
  __syncthreads();
  computeQ(0, 0); packQ(1); loadQ(2);
  __syncthreads();
  computeQ(1, 1); packQ(0); loadQ(3);
  __syncthreads();
  computeQ(2, 0); packQ(1);
  __syncthreads();
  computeQ(3, 1);

  // ---------- layer 2 B prefetch (hoisted above epilogue-1 barrier) ----------
  int mr2 = (w & 1) * 32;
  int nc2 = (w >> 1) * 96;
  const u16* Wb2 = W2t + ((size_t)e * N2 + (nc2 + lr)) * N1 + kg * 8;
  auto loadB2 = [&](int k0, short8 (&b)[6]) {
#pragma unroll
    for (int ni = 0; ni < 6; ++ni)
      b[ni] = *(const short8*)(Wb2 + (size_t)ni * 16 * N1 + k0);
  };
  short8 c2A[6], c2B[6], c2C[6], c2D[6];
  loadB2(0, c2A); loadB2(32, c2B); loadB2(64, c2C); loadB2(96, c2D);

  // epilogue 1 -> H1 (S[0]; its A-quarter data dead: last read was computeQ(2,0))
#pragma unroll
  for (int ni = 0; ni < 4; ++ni) {
    int col = w * 64 + ni * 16 + lr;
    float bias = b1[e * N1 + col];
#pragma unroll
    for (int mi = 0; mi < 4; ++mi)
#pragma unroll
      for (int r = 0; r < 4; ++r)
        H1[(mi * 16 + kg * 4 + r) * AP + col] = f2bf(celu_f(acc[mi][ni][r] + bias));
  }
  __syncthreads();

  // ---------- layer 2: 8 steps fully unrolled, 4-deep B ring, no barriers ----------
  f32x4 acc2[2][6] = {};
  auto mm2 = [&](int k0, short8 (&b)[6]) {
    short8 a0 = *(const short8*)&H1[(mr2 + lr) * AP + k0 + kg * 8];
    short8 a1 = *(const short8*)&H1[(mr2 + 16 + lr) * AP + k0 + kg * 8];
#pragma unroll
    for (int ni = 0; ni < 6; ++ni) {
      acc2[0][ni] = __builtin_amdgcn_mfma_f32_16x16x32_bf16(a0, b[ni], acc2[0][ni], 0, 0, 0);
      acc2[1][ni] = __builtin_amdgcn_mfma_f32_16x16x32_bf16(a1, b[ni], acc2[1][ni], 0, 0, 0);
    }
  };
  mm2(0, c2A);   loadB2(128, c2A);
  mm2(32, c2B);  loadB2(160, c2B);
  mm2(64, c2C);  loadB2(192, c2C);
  mm2(96, c2D);  loadB2(224, c2D);
  mm2(128, c2A);
  mm2(160, c2B);
  mm2(192, c2C);
  mm2(224, c2D);

  // ---------- layer 3 B prefetch (hoisted above epilogue-2 barrier) ----------
  int mr3 = (w & 1) * 32;
  int nc3 = (w >> 1) * 80;
  const u16* Wb3 = W3t + ((size_t)e * N3 + (nc3 + lr)) * N2 + kg * 8;
  auto loadB3 = [&](int k0, short8 (&b)[5]) {
#pragma unroll
    for (int ni = 0; ni < 5; ++ni)
      b[ni] = *(const short8*)(Wb3 + (size_t)ni * 16 * N2 + k0);
  };
  short8 c3A[5], c3B[5], c3C[5];
  loadB3(0, c3A); loadB3(32, c3B); loadB3(64, c3C);

  // epilogue 2 -> H2 (S[1]; its A-quarter data dead: last read was computeQ(3,1))
#pragma unroll
  for (int ni = 0; ni < 6; ++ni) {
    int col = nc2 + ni * 16 + lr;
    float bias = b2[e * N2 + col];
#pragma unroll
    for (int mi = 0; mi < 2; ++mi)
#pragma unroll
      for (int r = 0; r < 4; ++r)
        H2[(mr2 + mi * 16 + kg * 4 + r) * H2P + col] = f2bf(celu_f(acc2[mi][ni][r] + bias));
  }
  __syncthreads();

  // ---------- layer 3: 6 steps fully unrolled, 3-deep B ring, no barriers ----------
  f32x4 acc3[2][5] = {};
  auto mm3 = [&](int k0, short8 (&b)[5]) {
    short8 a0 = *(const short8*)&H2[(mr3 + lr) * H2P + k0 + kg * 8];
    short8 a1 = *(const short8*)&H2[(mr3 + 16 + lr) * H2P + k0 + kg * 8];
#pragma unroll
    for (int ni = 0; ni < 5; ++ni) {
      acc3[0][ni] = __builtin_amdgcn_mfma_f32_16x16x32_bf16(a0, b[ni], acc3[0][ni], 0, 0, 0);
      acc3[1][ni] = __builtin_amdgcn_mfma_f32_16x16x32_bf16(a1, b[ni], acc3[1][ni], 0, 0, 0);
    }
  };
  mm3(0, c3A);   loadB3(96, c3A);
  mm3(32, c3B);  loadB3(128, c3B);
  mm3(64, c3C);  loadB3(160, c3C);
  mm3(96, c3A);
  mm3(128, c3B);
  mm3(160, c3C);

  // ---------- head weights prefetch (hoisted above epilogue-3 barrier) ----------
  int hr_ = tid >> 2;
  int ho = (tid >> 1) & 1;
  int kh = tid & 1;
  const u16* wr = Wht + ((size_t)e * 2 + ho) * N3 + kh * 80;
  ushortx8 wvv[10];
#pragma unroll
  for (int c = 0; c < 10; ++c) wvv[c] = *(const ushortx8*)&wr[c * 8];

  // epilogue 3 -> H3 (S[0], over h1; all h1 reads ended before epi-2 barrier)
#pragma unroll
  for (int ni = 0; ni < 5; ++ni) {
    int col = nc3 + ni * 16 + lr;
    float bias = b3[e * N3 + col];
#pragma unroll
    for (int mi = 0; mi < 2; ++mi)
#pragma unroll
      for (int r = 0; r < 4; ++r)
        H3[(mr3 + mi * 16 + kg * 4 + r) * H3P + col] = f2bf(celu_f(acc3[mi][ni][r] + bias));
  }
  __syncthreads();

  // ---------- head ----------
  {
    float s = 0.f;
    const u16* hrow = &H3[hr_ * H3P + kh * 80];
#pragma unroll
    for (int c = 0; c < 10; ++c) {
      ushortx8 hv = *(const ushortx8*)&hrow[c * 8];
#pragma unroll
      for (int j = 0; j < 8; ++j) s += bf2f(hv[j]) * bf2f(wvv[c][j]);
    }
    s += __shfl_xor(s, 1);
    if (kh == 0 && hr_ < mcount) out[(size_t)idx[base + hr_] * 2 + ho] = s + bh[e * 2 + ho];
  }
}

extern "C" void kernel_launch(void* const* d_in, const int* in_sizes, int n_in,
                              void* d_out, int out_size, void* d_ws, size_t ws_size,
                              hipStream_t stream) {
  const int* species = (const int*)d_in[0];
  const float* aev = (const float*)d_in[1];
  const float* W1 = (const float*)d_in[2];
  const float* b1 = (const float*)d_in[3];
  const float* W2 = (const float*)d_in[4];
  const float* b2 = (const float*)d_in[5];
  const float* W3 = (const float*)d_in[6];
  const float* b3 = (const float*)d_in[7];
  const float* Wh = (const float*)d_in[8];
  const float* bh = (const float*)d_in[9];
  float* out = (float*)d_out;

  char* p = (char*)d_ws;
  int* counts = (int*)p; p += 32;
  int* offsets = (int*)p; p += 32;
  int* cursors = (int*)p; p += 32;
  int* blockStart = (int*)p; p += 32;
  int* idx = (int*)p; p += (size_t)NA * 4;
  u16* W1t = (u16*)p; p += (size_t)NS * N1 * KP1 * 2;
  u16* W2t = (u16*)p; p += (size_t)NS * N2 * N1 * 2;
  u16* W3t = (u16*)p; p += (size_t)NS * N3 * N2 * 2;
  u16* Wht = (u16*)p; p += (size_t)NS * 2 * N3 * 2;

  (void)hipMemsetAsync(counts, 0, 32, stream);
  count_kernel<<<NA / 256, 256, 0, stream>>>(species, counts);
  scan_kernel<<<1, 1, 0, stream>>>(counts, offsets, cursors, blockStart);
  scatter_kernel<<<NA / 256, 256, 0, stream>>>(species, cursors, idx);

  convert_w<<<2048, 256, 0, stream>>>(W1, W1t, AEVD, N1, KP1);
  convert_w<<<1024, 256, 0, stream>>>(W2, W2t, N1, N2, N1);
  convert_w<<<512, 256, 0, stream>>>(W3, W3t, N2, N3, N2);
  convert_w<<<16, 256, 0, stream>>>(Wh, Wht, N3, 2, N3);

  int maxBlocks = (NA >> 6) + NS;
  ani_fused<<<maxBlocks, 256, 0, stream>>>(idx, counts, offsets, blockStart, aev,
                                           W1t, b1, W2t, b2, W3t, b3, Wht, bh, out);
}